// Round 12
// baseline (239.229 us; speedup 1.0000x reference)
//
#include <hip/hip_runtime.h>
#include <math.h>

// Dims fixed by setup_inputs: d_model=1024, d_inner=2048, d_state=16,
// d_conv=4, dt_rank=64, B=2, L=1024. Tokens T = 2048.
#define DM 1024
#define DI 2048
#define DS 16
#define DTR 64
#define NB 2
#define LL 1024
#define TT (NB*LL)
#define SCH 32            // scan chunk length -> 512 blocks -> 2/CU
#define NCH (LL/SCH)      // 32 chunks per sequence

typedef unsigned short u16;
typedef __attribute__((ext_vector_type(8))) short bf16x8;
typedef __attribute__((ext_vector_type(4))) float f32x4;

#define LOG2E 1.4426950408889634f
#define LN2   0.6931471805599453f

__device__ inline u16 f2bf(float f) {   // RNE f32->bf16
  union { float f; unsigned u; } c; c.f = f;
  unsigned u = c.u;
  return (u16)((u + 0x7fffu + ((u >> 16) & 1u)) >> 16);
}
__device__ inline float bf2f(u16 u) {
  union { unsigned u; float f; } c; c.u = ((unsigned)u) << 16;
  return c.f;
}

// fast SiLU: x * rcp(1 + exp2(-x*log2e)) -- HW v_exp/v_rcp, plenty for bf16
__device__ inline float fsilu(float x) {
  return x * __builtin_amdgcn_rcpf(1.0f + __builtin_amdgcn_exp2f(-x * LOG2E));
}

// order-preserving f32 <-> u32 key (for atomicMin-based global min)
__device__ inline unsigned fkey(float f) {
  union { float f; unsigned u; } c; c.f = f;
  return (c.u & 0x80000000u) ? ~c.u : (c.u | 0x80000000u);
}
__device__ inline float funkey(unsigned k) {
  union { unsigned u; float f; } c;
  c.u = (k & 0x80000000u) ? (k & 0x7fffffffu) : ~k;
  return c.f;
}

__device__ inline bf16x8 cvt8(float4 a, float4 b) {
  bf16x8 w;
  w[0] = (short)f2bf(a.x); w[1] = (short)f2bf(a.y);
  w[2] = (short)f2bf(a.z); w[3] = (short)f2bf(a.w);
  w[4] = (short)f2bf(b.x); w[5] = (short)f2bf(b.y);
  w[6] = (short)f2bf(b.z); w[7] = (short)f2bf(b.w);
  return w;
}

#define GLDS16(g, l) __builtin_amdgcn_global_load_lds( \
    (const __attribute__((address_space(1))) unsigned int*)(g), \
    (__attribute__((address_space(3))) unsigned int*)(l), 16, 0, 0)

// ---------------------------------------------------------------------------
// bf16 MFMA GEMM.
// ASRC: 0 = bf16 A via global_load_lds; 1 = fp32 A reg-staged.
// B always bf16 via global_load_lds (round-6 lesson).
// EPI=1: clip(softplus(v+bias[col]),1e-4,20).
// OB=1: bf16 store. OB=2: fp32 atomicAdd; if CGd>0 only cols<CGd, ldc=CGd.
// BMIN=1: flat blocks 0..63 reduce min over minsrc cols 64..79.
// PIPE3=1: 3-buffer LDS, 2-tiles-in-flight, counted vmcnt(SPW) (T4).
//          ASRC=0, SPW in {3,4}.
// NOTE round-12: XCD swizzle (T1) REMOVED — whole working set (~70 MB) is
// L3-resident, and T1 costs ~2% in the L3-fit regime (catalog m160); round-11
// measured exactly that (+1.5 us).
// ---------------------------------------------------------------------------
template<int BM, int BN, int EPI, int OB, int CGd, int ASRC, int BMIN, int PIPE3>
__global__ __launch_bounds__(256) void gemm_k(
    const void* __restrict__ Av, const u16* __restrict__ B,
    void* __restrict__ Cv, int M, int N, int K, int lda, int ldb, int kpb,
    const float* __restrict__ bias,
    const float* __restrict__ minsrc, unsigned* __restrict__ betakey) {
  constexpr int WAVES_M = BM / 64;
  constexpr int WAVES_N = 4 / WAVES_M;
  constexpr int WTM = 4;
  constexpr int WTN = BN / (WAVES_N * 16);
  constexpr int ASLABS = BM / 16;
  constexpr int SLABS = (BM + BN) / 16;
  constexpr int SPW = SLABS / 4;
  constexpr int NBUF = PIPE3 ? 3 : 2;
  static_assert(!PIPE3 || (ASRC == 0 && (SPW == 3 || SPW == 4)),
                "PIPE3 needs ASRC=0, SPW in {3,4}");
  __shared__ u16 As[NBUF][BM * 32];
  __shared__ u16 Bs[NBUF][BN * 32];
  __shared__ float sm4[4];
  const int tid = threadIdx.x;
  const int wave = tid >> 6;
  const int lane = tid & 63;
  const int bm = blockIdx.y * BM;
  const int bn = blockIdx.x * BN;
  const int wm = (wave / WAVES_N) * 64;
  const int wn = (wave % WAVES_N) * (WTN * 16);
  const int r4 = lane >> 2;
  const int kc = (lane & 3) * 8;
  const int fr = lane & 15;
  const int fq = lane >> 4;
  const int koff = blockIdx.z * kpb;
  float* C = (float*)Cv;
  u16* C16 = (u16*)Cv;

  if constexpr (BMIN == 1) {   // beta-min prologue (flat blocks 0..63)
    int fb = blockIdx.y * gridDim.x + blockIdx.x;
    if (fb < 64) {
      const int t0 = fb * 32;
      float mn = 3.4e38f;
      for (int i = tid; i < 32 * 16; i += 256) {
        int t = t0 + (i >> 4), n = i & 15;
        mn = fminf(mn, minsrc[t * 96 + 64 + n]);
      }
#pragma unroll
      for (int o = 32; o; o >>= 1) mn = fminf(mn, __shfl_down(mn, o));
      if ((tid & 63) == 0) sm4[tid >> 6] = mn;
      __syncthreads();
      if (tid == 0)
        atomicMin(betakey, fkey(fminf(fminf(sm4[0], sm4[1]), fminf(sm4[2], sm4[3]))));
      __syncthreads();
    }
  }

  auto stage = [&](int k0, int bufi) {
#pragma unroll
    for (int s = wave * SPW; s < (wave + 1) * SPW; ++s) {
      if (s < ASLABS) {
        int row = s * 16 + r4;
        if constexpr (ASRC == 0) {
          GLDS16((const u16*)Av + (size_t)(bm + row) * lda + k0 + kc,
                 &As[bufi][s * 512]);
        } else {
          const float* src = (const float*)Av + (size_t)(bm + row) * lda + k0 + kc;
          float4 v0 = *(const float4*)src;
          float4 v1 = *(const float4*)(src + 4);
          *(bf16x8*)&As[bufi][s * 512 + lane * 8] = cvt8(v0, v1);
        }
      } else {
        int bs = s - ASLABS;
        int row = bs * 16 + r4;
        GLDS16(B + (size_t)(bn + row) * ldb + k0 + kc, &Bs[bufi][bs * 512]);
      }
    }
  };

  f32x4 acc[WTM][WTN];
#pragma unroll
  for (int i = 0; i < WTM; ++i)
#pragma unroll
    for (int j = 0; j < WTN; ++j) acc[i][j] = (f32x4){0.f, 0.f, 0.f, 0.f};

  const int NT = kpb >> 5;

  auto compute = [&](int cur) {
    bf16x8 af[WTM], bf[WTN];
#pragma unroll
    for (int i = 0; i < WTM; ++i)
      af[i] = *(const bf16x8*)&As[cur][(wm + 16 * i + fr) * 32 + fq * 8];
#pragma unroll
    for (int j = 0; j < WTN; ++j)
      bf[j] = *(const bf16x8*)&Bs[cur][(wn + 16 * j + fr) * 32 + fq * 8];
#pragma unroll
    for (int i = 0; i < WTM; ++i)
#pragma unroll
      for (int j = 0; j < WTN; ++j)
        acc[i][j] = __builtin_amdgcn_mfma_f32_16x16x32_bf16(af[i], bf[j], acc[i][j], 0, 0, 0);
  };

  if constexpr (PIPE3) {
    // 3-buffer, 2 tiles in flight, counted vmcnt(SPW): the wait covers loads
    // issued a FULL iteration earlier; the newest tile stays in flight.
    stage(koff, 0);
    stage(koff + 32, 1);
    if constexpr (SPW == 4) asm volatile("s_waitcnt vmcnt(4)" ::: "memory");
    else                    asm volatile("s_waitcnt vmcnt(3)" ::: "memory");
    __builtin_amdgcn_s_barrier();
    for (int t = 0; t < NT; ++t) {
      const int cur = t % 3;
      if (t + 2 < NT) stage(koff + (t + 2) * 32, (t + 2) % 3);
      compute(cur);
      if (t + 1 < NT) {
        if (t + 2 < NT) {
          if constexpr (SPW == 4) asm volatile("s_waitcnt vmcnt(4)" ::: "memory");
          else                    asm volatile("s_waitcnt vmcnt(3)" ::: "memory");
        } else {
          asm volatile("s_waitcnt vmcnt(0)" ::: "memory");
        }
        __builtin_amdgcn_s_barrier();
      }
    }
  } else {
    // 2-phase (round-8 proven)
    stage(koff, 0);
    asm volatile("s_waitcnt vmcnt(0) lgkmcnt(0)" ::: "memory");
    __builtin_amdgcn_s_barrier();
    for (int t = 0; t < NT; ++t) {
      const int cur = t & 1;
      if (t + 1 < NT) stage(koff + (t + 1) * 32, cur ^ 1);
      compute(cur);
      if (t + 1 < NT) {
        asm volatile("s_waitcnt vmcnt(0) lgkmcnt(0)" ::: "memory");
        __builtin_amdgcn_s_barrier();
      }
    }
  }

#pragma unroll
  for (int i = 0; i < WTM; ++i) {
    int row0 = bm + wm + 16 * i + fq * 4;
#pragma unroll
    for (int j = 0; j < WTN; ++j) {
      int col = bn + wn + 16 * j + fr;
#pragma unroll
      for (int r = 0; r < 4; ++r) {
        float v = acc[i][j][r];
        if (EPI == 1) {
          v += bias[col];
          float sp;
          if (v > 20.0f) sp = v;
          else sp = __builtin_amdgcn_logf(1.0f + __builtin_amdgcn_exp2f(v * LOG2E)) * LN2;
          v = fminf(fmaxf(sp, 1e-4f), 20.0f);
        }
        if (OB == 1) {
          C16[(size_t)(row0 + r) * N + col] = f2bf(v);
        } else {  // OB == 2
          if (CGd == 0 || col < CGd) {
            const int ldc = (CGd > 0) ? CGd : N;
            atomicAdd(&C[(size_t)(row0 + r) * ldc + col], v);
          }
        }
      }
    }
  }
}

// ---------------------------------------------------------------------------
// Fused bf16 casts + zero-inits: hs, W_in, W_out, W_x (pad to 128 rows),
// W_dt; zero xdb (atomic target) and out (atomic target); init betakey.
// ---------------------------------------------------------------------------
__global__ __launch_bounds__(256) void cast_all(
    const float* __restrict__ hs, const float* __restrict__ win,
    const float* __restrict__ wout, const float* __restrict__ wx,
    const float* __restrict__ wdt,
    u16* __restrict__ hs_bf, u16* __restrict__ win_bf,
    u16* __restrict__ wout_bf, u16* __restrict__ wx_bf,
    u16* __restrict__ wdt_bf, float* __restrict__ xdb,
    float* __restrict__ outz, unsigned* __restrict__ betakey) {
  int gid = blockIdx.x * 256 + threadIdx.x;  // 2,768,896 total
  if (gid == 0) betakey[0] = 0xFFFFFFFFu;
  const float* src; u16* dst; int off;
  if (gid < 524288)       { src = hs;   dst = hs_bf;   off = gid; }
  else if (gid < 1572864) { src = win;  dst = win_bf;  off = gid - 524288; }
  else if (gid < 2097152) { src = wout; dst = wout_bf; off = gid - 1572864; }
  else if (gid < 2146304) { src = wx;   dst = wx_bf;   off = gid - 2097152; }
  else if (gid < 2179072) { src = wdt;  dst = wdt_bf;  off = gid - 2146304; }
  else if (gid < 2195456) {  // zero-fill wx_bf rows 96..127
    ushort4 z4 = {0, 0, 0, 0};
    ((ushort4*)wx_bf)[49152 + gid - 2179072] = z4;
    return;
  } else if (gid < 2244608) {  // zero xdb (196,608 f)
    float4 z = {0.f, 0.f, 0.f, 0.f};
    ((float4*)xdb)[gid - 2195456] = z;
    return;
  } else {                     // zero out (2,097,152 f)
    float4 z = {0.f, 0.f, 0.f, 0.f};
    ((float4*)outz)[gid - 2244608] = z;
    return;
  }
  float4 v = ((const float4*)src)[off];
  ushort4 o;
  o.x = f2bf(v.x); o.y = f2bf(v.y); o.z = f2bf(v.z); o.w = f2bf(v.w);
  ((ushort4*)dst)[off] = o;
}

// ---------------------------------------------------------------------------
// Causal depthwise conv (k=4, pad 3) + bias + SiLU. bf16 in, bf16 out.
// 8 channels/thread (16B loads, G13). 2048 blocks = 8/CU.
// ---------------------------------------------------------------------------
__global__ __launch_bounds__(256) void conv_silu4(
    const u16* __restrict__ xz, const float* __restrict__ w,
    const float* __restrict__ cb, u16* __restrict__ xc_bf) {
  int gid = blockIdx.x * 256 + threadIdx.x;  // TT*256
  int dq = (gid & 255) * 8;
  int t = gid >> 8;
  int l = t & (LL - 1);
  float wv[8][4];
#pragma unroll
  for (int j = 0; j < 8; ++j) {
    float4 ww = *(const float4*)&w[(dq + j) * 4];
    wv[j][0] = ww.x; wv[j][1] = ww.y; wv[j][2] = ww.z; wv[j][3] = ww.w;
  }
  float acc[8];
#pragma unroll
  for (int j = 0; j < 8; ++j) acc[j] = cb[dq + j];
#pragma unroll
  for (int k = 0; k < 4; ++k) {
    int ll = l - 3 + k;
    if (ll < 0) continue;
    bf16x8 xv = *(const bf16x8*)&xz[(size_t)(t - 3 + k) * (2 * DI) + dq];
#pragma unroll
    for (int j = 0; j < 8; ++j) acc[j] += bf2f((u16)xv[j]) * wv[j][k];
  }
  bf16x8 o;
#pragma unroll
  for (int j = 0; j < 8; ++j) o[j] = (short)f2bf(fsilu(acc[j]));
  *(bf16x8*)&xc_bf[(size_t)t * DI + dq] = o;
}

// ---------------------------------------------------------------------------
// Chunked selective scan, SCH=32 (512 blocks/pass -> 2/CU). 3 kernels.
// ---------------------------------------------------------------------------
__global__ __launch_bounds__(256) void scan_pass1(
    const u16* __restrict__ delta, const u16* __restrict__ xc_bf,
    const float* __restrict__ xdb, const float* __restrict__ A_log,
    const unsigned* __restrict__ betak,
    float* __restrict__ hend, float* __restrict__ Ssum) {
  const int d = blockIdx.x * 256 + threadIdx.x;
  const int c = blockIdx.y;
  const int b = blockIdx.z;
  __shared__ float Bsh[SCH][16];
  const float beta = fmaxf(0.0f, -funkey(betak[0]));
  const int t0 = b * LL + c * SCH;
  for (int i = threadIdx.x; i < SCH * 16; i += 256) {
    int tt = i >> 4, n = i & 15;
    Bsh[tt][n] = xdb[(size_t)(t0 + tt) * 96 + 64 + n] + beta;
  }
  __syncthreads();
  float Av2[16];
#pragma unroll
  for (int n = 0; n < 16; ++n)
    Av2[n] = __builtin_amdgcn_exp2f(A_log[d * 16 + n] * LOG2E) * LOG2E;
  float h[16];
#pragma unroll
  for (int n = 0; n < 16; ++n) h[n] = 0.f;
  float S = 0.f;
  for (int tt = 0; tt < SCH; ++tt) {
    int t = t0 + tt;
    float dv = bf2f(delta[(size_t)t * DI + d]);
    float xv = bf2f(xc_bf[(size_t)t * DI + d]);
    float dx = dv * xv;
    S += dv;
#pragma unroll
    for (int n = 0; n < 16; ++n) {
      float a = __builtin_amdgcn_exp2f(-dv * Av2[n]);
      h[n] = a * h[n] + dx * Bsh[tt][n];
    }
  }
  size_t base = (((size_t)(b * NCH + c) * DI) + d) * 16;
#pragma unroll
  for (int n = 0; n < 16; ++n) hend[base + n] = h[n];
  Ssum[((size_t)(b * NCH + c) * DI) + d] = S;
}

__global__ __launch_bounds__(256) void scan_pass2(
    float* __restrict__ hend, const float* __restrict__ Ssum,
    const float* __restrict__ A_log) {
  int gid = blockIdx.x * 256 + threadIdx.x;   // 65536
  int n = gid & 15;
  int d = (gid >> 4) & (DI - 1);
  int b = gid >> 15;
  float Av2 = __builtin_amdgcn_exp2f(A_log[d * 16 + n] * LOG2E) * LOG2E;
  float H = 0.f;
  for (int c = 0; c < NCH; ++c) {
    size_t cb = ((size_t)(b * NCH + c) * DI) + d;
    float hl = hend[cb * 16 + n];
    float p = __builtin_amdgcn_exp2f(-Av2 * Ssum[cb]);
    hend[cb * 16 + n] = H;
    H = p * H + hl;
  }
}

__global__ __launch_bounds__(256) void scan_pass3(
    const u16* __restrict__ delta, const u16* __restrict__ xc_bf,
    const float* __restrict__ xdb, const u16* __restrict__ xz_bf,
    const float* __restrict__ A_log, const float* __restrict__ Dp,
    const unsigned* __restrict__ betak, const float* __restrict__ hstart,
    u16* __restrict__ ybf) {
  const int d = blockIdx.x * 256 + threadIdx.x;
  const int c = blockIdx.y;
  const int b = blockIdx.z;
  __shared__ float Bsh[SCH][16];
  __shared__ float Csh[SCH][16];
  const float beta = fmaxf(0.0f, -funkey(betak[0]));
  const int t0 = b * LL + c * SCH;
  for (int i = threadIdx.x; i < SCH * 16; i += 256) {
    int tt = i >> 4, n = i & 15;
    size_t row = (size_t)(t0 + tt) * 96;
    Bsh[tt][n] = xdb[row + 64 + n] + beta;
    Csh[tt][n] = xdb[row + 80 + n];
  }
  __syncthreads();
  float Av2[16];
#pragma unroll
  for (int n = 0; n < 16; ++n)
    Av2[n] = __builtin_amdgcn_exp2f(A_log[d * 16 + n] * LOG2E) * LOG2E;
  float h[16];
  size_t base = (((size_t)(b * NCH + c) * DI) + d) * 16;
#pragma unroll
  for (int n = 0; n < 16; ++n) h[n] = hstart[base + n];
  const float Dd = Dp[d];
  for (int tt = 0; tt < SCH; ++tt) {
    int t = t0 + tt;
    float dv = bf2f(delta[(size_t)t * DI + d]);
    float xv = bf2f(xc_bf[(size_t)t * DI + d]);
    float dx = dv * xv;
    float yv = 0.f;
#pragma unroll
    for (int n = 0; n < 16; ++n) {
      float a = __builtin_amdgcn_exp2f(-dv * Av2[n]);
      h[n] = a * h[n] + dx * Bsh[tt][n];
      yv += h[n] * Csh[tt][n];
    }
    float zv = bf2f(xz_bf[(size_t)t * (2 * DI) + DI + d]);
    float out = (yv + xv * Dd) * fsilu(zv);
    ybf[(size_t)t * DI + d] = f2bf(out);
  }
}

extern "C" void kernel_launch(void* const* d_in, const int* in_sizes, int n_in,
                              void* d_out, int out_size, void* d_ws, size_t ws_size,
                              hipStream_t stream) {
  const float* hs      = (const float*)d_in[0];
  const float* W_in    = (const float*)d_in[1];
  const float* conv_w  = (const float*)d_in[2];
  const float* conv_b  = (const float*)d_in[3];
  const float* W_x     = (const float*)d_in[4];
  const float* W_dt    = (const float*)d_in[5];
  const float* dt_bias = (const float*)d_in[6];
  const float* W_out   = (const float*)d_in[7];
  const float* A_log   = (const float*)d_in[8];
  const float* Dp      = (const float*)d_in[9];
  float* out = (float*)d_out;

  float* ws       = (float*)d_ws;
  float* xz_bfR   = ws;                                  // 4,194,304 f
  float* xcv_bfR  = xz_bfR + (size_t)TT * 2 * DI / 2;    // 2,097,152 f
  float* xdb      = xcv_bfR + (size_t)TT * DI / 2;       //   196,608 f
  float* dlt_bfR  = xdb + (size_t)TT * 96;               // 2,097,152 f
  float* betab    = dlt_bfR + (size_t)TT * DI / 2;       //        64 f
  float* hend     = betab + 64;                          // 2,097,152 f
  float* Ssum     = hend + (size_t)NB * NCH * DI * 16;   //   131,072 f
  float* hs_bfR   = Ssum + (size_t)NB * NCH * DI;        // 1,048,576 f
  float* win_bfR  = hs_bfR + (size_t)TT * DM / 2;        // 2,097,152 f
  float* wout_bfR = win_bfR + (size_t)2 * DI * DM / 2;   // 1,048,576 f
  float* wx_bfR   = wout_bfR + (size_t)DM * DI / 2;      //   131,072 f
  float* wdt_bfR  = wx_bfR + 131072;                     //    65,536 f

  u16* xz_bf   = (u16*)xz_bfR;
  u16* xcv_bf  = (u16*)xcv_bfR;
  u16* dlt_bf  = (u16*)dlt_bfR;
  u16* hs_bf   = (u16*)hs_bfR;
  u16* win_bf  = (u16*)win_bfR;
  u16* wout_bf = (u16*)wout_bfR;
  u16* wx_bf   = (u16*)wx_bfR;
  u16* wdt_bf  = (u16*)wdt_bfR;
  unsigned* betakey = (unsigned*)betab;
  u16* ybf     = (u16*)win_bfR;   // aliases win_bf (dead after GEMM1)

  dim3 blk(256);

  // 1) bf16 casts + zero xdb/out + betakey init
  cast_all<<<10816, blk, 0, stream>>>(hs, W_in, W_out, W_x, W_dt,
                                      hs_bf, win_bf, wout_bf, wx_bf, wdt_bf,
                                      xdb, out, betakey);

  // 2) xz = hs @ W_in^T  (2048x4096x1024) bf16 GLDS, PIPE3 (no swizzle)
  gemm_k<128, 128, 0, 1, 0, 0, 0, 1>
      <<<dim3(4096 / 128, TT / 128), blk, 0, stream>>>(
      hs_bf, win_bf, xz_bf, TT, 2 * DI, DM, DM, DM, DM,
      nullptr, nullptr, nullptr);

  // 3) conv + silu -> xcv_bf (standalone; bf16x8, 8 ch/thread)
  conv_silu4<<<(TT * DI / 8) / 256, blk, 0, stream>>>(xz_bf, conv_w, conv_b, xcv_bf);

  // 4) x_dbl: (2048x128x2048) bf16 GLDS, split-K=8, atomic cols<96, PIPE3
  gemm_k<64, 128, 0, 2, 96, 0, 0, 1>
      <<<dim3(1, TT / 64, 8), blk, 0, stream>>>(
      xcv_bf, wx_bf, xdb, TT, 128, DI, DI, DI, DI / 8,
      nullptr, nullptr, nullptr);

  // 5) delta: A = xdb cols0..63 fp32 reg-staged (lda=96), B = wdt_bf GLDS,
  //    softplus/clip -> bf16 dlt; blocks 0..63 also reduce beta-min (BMIN)
  gemm_k<64, 128, 1, 1, 0, 1, 1, 0>
      <<<dim3(DI / 128, TT / 64), blk, 0, stream>>>(
      xdb, wdt_bf, dlt_bf, TT, DI, DTR, 96, DTR, DTR,
      dt_bias, xdb, betakey);

  // 6) chunked selective scan -> ybf
  scan_pass1<<<dim3(DI / 256, NCH, NB), blk, 0, stream>>>(
      dlt_bf, xcv_bf, xdb, A_log, betakey, hend, Ssum);
  scan_pass2<<<(NB * DI * DS) / 256, blk, 0, stream>>>(hend, Ssum, A_log);
  scan_pass3<<<dim3(DI / 256, NCH, NB), blk, 0, stream>>>(
      dlt_bf, xcv_bf, xdb, xz_bf, A_log, Dp, betakey, hend, ybf);

  // 7) out = y @ W_out^T (2048x1024x2048) GLDS, split-K=4 atomic, PIPE3
  gemm_k<128, 128, 0, 2, 0, 0, 0, 1>
      <<<dim3(DM / 128, TT / 128, 4), blk, 0, stream>>>(
      ybf, wout_bf, out, TT, DM, DI, DI, DI, DI / 4,
      nullptr, nullptr, nullptr);
}

// Round 13
// 236.573 us; speedup vs baseline: 1.0112x; 1.0112x over previous
//
#include <hip/hip_runtime.h>
#include <math.h>

// Dims fixed by setup_inputs: d_model=1024, d_inner=2048, d_state=16,
// d_conv=4, dt_rank=64, B=2, L=1024. Tokens T = 2048.
#define DM 1024
#define DI 2048
#define DS 16
#define DTR 64
#define NB 2
#define LL 1024
#define TT (NB*LL)
#define SCH 32            // scan chunk length -> 512 blocks -> 2/CU
#define NCH (LL/SCH)      // 32 chunks per sequence

typedef unsigned short u16;
typedef __attribute__((ext_vector_type(8))) short bf16x8;
typedef __attribute__((ext_vector_type(4))) float f32x4;

#define LOG2E 1.4426950408889634f
#define LN2   0.6931471805599453f

__device__ inline u16 f2bf(float f) {   // RNE f32->bf16
  union { float f; unsigned u; } c; c.f = f;
  unsigned u = c.u;
  return (u16)((u + 0x7fffu + ((u >> 16) & 1u)) >> 16);
}
__device__ inline float bf2f(u16 u) {
  union { unsigned u; float f; } c; c.u = ((unsigned)u) << 16;
  return c.f;
}

// fast SiLU: x * rcp(1 + exp2(-x*log2e)) -- HW v_exp/v_rcp, plenty for bf16
__device__ inline float fsilu(float x) {
  return x * __builtin_amdgcn_rcpf(1.0f + __builtin_amdgcn_exp2f(-x * LOG2E));
}

// order-preserving f32 <-> u32 key (for atomicMin-based global min)
__device__ inline unsigned fkey(float f) {
  union { float f; unsigned u; } c; c.f = f;
  return (c.u & 0x80000000u) ? ~c.u : (c.u | 0x80000000u);
}
__device__ inline float funkey(unsigned k) {
  union { unsigned u; float f; } c;
  c.u = (k & 0x80000000u) ? (k & 0x7fffffffu) : ~k;
  return c.f;
}

__device__ inline bf16x8 cvt8(float4 a, float4 b) {
  bf16x8 w;
  w[0] = (short)f2bf(a.x); w[1] = (short)f2bf(a.y);
  w[2] = (short)f2bf(a.z); w[3] = (short)f2bf(a.w);
  w[4] = (short)f2bf(b.x); w[5] = (short)f2bf(b.y);
  w[6] = (short)f2bf(b.z); w[7] = (short)f2bf(b.w);
  return w;
}

#define GLDS16(g, l) __builtin_amdgcn_global_load_lds( \
    (const __attribute__((address_space(1))) unsigned int*)(g), \
    (__attribute__((address_space(3))) unsigned int*)(l), 16, 0, 0)

// ---------------------------------------------------------------------------
// bf16 MFMA GEMM.  (Round-13: exact round-10 champion configuration.)
// ASRC: 0 = bf16 A via global_load_lds; 1 = fp32 A reg-staged.
// B always bf16 via global_load_lds (round-6 lesson: fp32 reg-staged B
// cost -26us+ on the big GEMM).
// EPI=1: clip(softplus(v+bias[col]),1e-4,20).
// OB=1: bf16 store. OB=2: fp32 atomicAdd; if CGd>0 only cols<CGd, ldc=CGd.
// BMIN=1: flat blocks 0..63 reduce min over minsrc cols 64..79 (betakey).
// PIPE3=1: 3-buffer LDS, 2-tiles-in-flight, counted vmcnt(4) (T4);
//          ASRC=0, SPW==4 only (128x128 tiles). Isolated A/B (r8 vs r10):
//          -2.3us. No XCD swizzle: working set is L3-resident; T1 costs ~2%
//          in that regime (catalog m160; measured +1.5us in r11).
// ---------------------------------------------------------------------------
template<int BM, int BN, int EPI, int OB, int CGd, int ASRC, int BMIN, int PIPE3>
__global__ __launch_bounds__(256) void gemm_k(
    const void* __restrict__ Av, const u16* __restrict__ B,
    void* __restrict__ Cv, int M, int N, int K, int lda, int ldb, int kpb,
    const float* __restrict__ bias,
    const float* __restrict__ minsrc, unsigned* __restrict__ betakey) {
  constexpr int WAVES_M = BM / 64;
  constexpr int WAVES_N = 4 / WAVES_M;
  constexpr int WTM = 4;
  constexpr int WTN = BN / (WAVES_N * 16);
  constexpr int ASLABS = BM / 16;
  constexpr int SLABS = (BM + BN) / 16;
  constexpr int SPW = SLABS / 4;
  constexpr int NBUF = PIPE3 ? 3 : 2;
  static_assert(!PIPE3 || (ASRC == 0 && SPW == 4), "PIPE3 needs ASRC=0, SPW=4");
  __shared__ u16 As[NBUF][BM * 32];
  __shared__ u16 Bs[NBUF][BN * 32];
  __shared__ float sm4[4];
  const int tid = threadIdx.x;
  const int wave = tid >> 6;
  const int lane = tid & 63;
  const int bm = blockIdx.y * BM;
  const int bn = blockIdx.x * BN;
  const int wm = (wave / WAVES_N) * 64;
  const int wn = (wave % WAVES_N) * (WTN * 16);
  const int r4 = lane >> 2;
  const int kc = (lane & 3) * 8;
  const int fr = lane & 15;
  const int fq = lane >> 4;
  const int koff = blockIdx.z * kpb;
  float* C = (float*)Cv;
  u16* C16 = (u16*)Cv;

  if constexpr (BMIN == 1) {   // beta-min prologue (flat blocks 0..63)
    int fb = blockIdx.y * gridDim.x + blockIdx.x;
    if (fb < 64) {
      const int t0 = fb * 32;
      float mn = 3.4e38f;
      for (int i = tid; i < 32 * 16; i += 256) {
        int t = t0 + (i >> 4), n = i & 15;
        mn = fminf(mn, minsrc[t * 96 + 64 + n]);
      }
#pragma unroll
      for (int o = 32; o; o >>= 1) mn = fminf(mn, __shfl_down(mn, o));
      if ((tid & 63) == 0) sm4[tid >> 6] = mn;
      __syncthreads();
      if (tid == 0)
        atomicMin(betakey, fkey(fminf(fminf(sm4[0], sm4[1]), fminf(sm4[2], sm4[3]))));
      __syncthreads();
    }
  }

  auto stage = [&](int k0, int bufi) {
#pragma unroll
    for (int s = wave * SPW; s < (wave + 1) * SPW; ++s) {
      if (s < ASLABS) {
        int row = s * 16 + r4;
        if constexpr (ASRC == 0) {
          GLDS16((const u16*)Av + (size_t)(bm + row) * lda + k0 + kc,
                 &As[bufi][s * 512]);
        } else {
          const float* src = (const float*)Av + (size_t)(bm + row) * lda + k0 + kc;
          float4 v0 = *(const float4*)src;
          float4 v1 = *(const float4*)(src + 4);
          *(bf16x8*)&As[bufi][s * 512 + lane * 8] = cvt8(v0, v1);
        }
      } else {
        int bs = s - ASLABS;
        int row = bs * 16 + r4;
        GLDS16(B + (size_t)(bn + row) * ldb + k0 + kc, &Bs[bufi][bs * 512]);
      }
    }
  };

  f32x4 acc[WTM][WTN];
#pragma unroll
  for (int i = 0; i < WTM; ++i)
#pragma unroll
    for (int j = 0; j < WTN; ++j) acc[i][j] = (f32x4){0.f, 0.f, 0.f, 0.f};

  const int NT = kpb >> 5;

  auto compute = [&](int cur) {
    bf16x8 af[WTM], bf[WTN];
#pragma unroll
    for (int i = 0; i < WTM; ++i)
      af[i] = *(const bf16x8*)&As[cur][(wm + 16 * i + fr) * 32 + fq * 8];
#pragma unroll
    for (int j = 0; j < WTN; ++j)
      bf[j] = *(const bf16x8*)&Bs[cur][(wn + 16 * j + fr) * 32 + fq * 8];
#pragma unroll
    for (int i = 0; i < WTM; ++i)
#pragma unroll
      for (int j = 0; j < WTN; ++j)
        acc[i][j] = __builtin_amdgcn_mfma_f32_16x16x32_bf16(af[i], bf[j], acc[i][j], 0, 0, 0);
  };

  if constexpr (PIPE3) {
    // 3-buffer, 2 tiles in flight, counted vmcnt: the wait covers loads
    // issued a FULL iteration earlier (fully latency-hidden), never the
    // just-issued ones. SPW=4 -> vmcnt(4) leaves newest tile in flight.
    stage(koff, 0);
    stage(koff + 32, 1);
    asm volatile("s_waitcnt vmcnt(4)" ::: "memory");
    __builtin_amdgcn_s_barrier();
    for (int t = 0; t < NT; ++t) {
      const int cur = t % 3;
      if (t + 2 < NT) stage(koff + (t + 2) * 32, (t + 2) % 3);
      compute(cur);
      if (t + 1 < NT) {
        if (t + 2 < NT) asm volatile("s_waitcnt vmcnt(4)" ::: "memory");
        else            asm volatile("s_waitcnt vmcnt(0)" ::: "memory");
        __builtin_amdgcn_s_barrier();
      }
    }
  } else {
    // 2-phase (round-8 proven)
    stage(koff, 0);
    asm volatile("s_waitcnt vmcnt(0) lgkmcnt(0)" ::: "memory");
    __builtin_amdgcn_s_barrier();
    for (int t = 0; t < NT; ++t) {
      const int cur = t & 1;
      if (t + 1 < NT) stage(koff + (t + 1) * 32, cur ^ 1);
      compute(cur);
      if (t + 1 < NT) {
        asm volatile("s_waitcnt vmcnt(0) lgkmcnt(0)" ::: "memory");
        __builtin_amdgcn_s_barrier();
      }
    }
  }

#pragma unroll
  for (int i = 0; i < WTM; ++i) {
    int row0 = bm + wm + 16 * i + fq * 4;
#pragma unroll
    for (int j = 0; j < WTN; ++j) {
      int col = bn + wn + 16 * j + fr;
#pragma unroll
      for (int r = 0; r < 4; ++r) {
        float v = acc[i][j][r];
        if (EPI == 1) {
          v += bias[col];
          float sp;
          if (v > 20.0f) sp = v;
          else sp = __builtin_amdgcn_logf(1.0f + __builtin_amdgcn_exp2f(v * LOG2E)) * LN2;
          v = fminf(fmaxf(sp, 1e-4f), 20.0f);
        }
        if (OB == 1) {
          C16[(size_t)(row0 + r) * N + col] = f2bf(v);
        } else {  // OB == 2
          if (CGd == 0 || col < CGd) {
            const int ldc = (CGd > 0) ? CGd : N;
            atomicAdd(&C[(size_t)(row0 + r) * ldc + col], v);
          }
        }
      }
    }
  }
}

// ---------------------------------------------------------------------------
// Fused bf16 casts + zero-inits: hs, W_in, W_out, W_x (pad to 128 rows),
// W_dt; zero xdb (atomic target) and out (atomic target); init betakey.
// ---------------------------------------------------------------------------
__global__ __launch_bounds__(256) void cast_all(
    const float* __restrict__ hs, const float* __restrict__ win,
    const float* __restrict__ wout, const float* __restrict__ wx,
    const float* __restrict__ wdt,
    u16* __restrict__ hs_bf, u16* __restrict__ win_bf,
    u16* __restrict__ wout_bf, u16* __restrict__ wx_bf,
    u16* __restrict__ wdt_bf, float* __restrict__ xdb,
    float* __restrict__ outz, unsigned* __restrict__ betakey) {
  int gid = blockIdx.x * 256 + threadIdx.x;  // 2,768,896 total
  if (gid == 0) betakey[0] = 0xFFFFFFFFu;
  const float* src; u16* dst; int off;
  if (gid < 524288)       { src = hs;   dst = hs_bf;   off = gid; }
  else if (gid < 1572864) { src = win;  dst = win_bf;  off = gid - 524288; }
  else if (gid < 2097152) { src = wout; dst = wout_bf; off = gid - 1572864; }
  else if (gid < 2146304) { src = wx;   dst = wx_bf;   off = gid - 2097152; }
  else if (gid < 2179072) { src = wdt;  dst = wdt_bf;  off = gid - 2146304; }
  else if (gid < 2195456) {  // zero-fill wx_bf rows 96..127
    ushort4 z4 = {0, 0, 0, 0};
    ((ushort4*)wx_bf)[49152 + gid - 2179072] = z4;
    return;
  } else if (gid < 2244608) {  // zero xdb (196,608 f)
    float4 z = {0.f, 0.f, 0.f, 0.f};
    ((float4*)xdb)[gid - 2195456] = z;
    return;
  } else {                     // zero out (2,097,152 f)
    float4 z = {0.f, 0.f, 0.f, 0.f};
    ((float4*)outz)[gid - 2244608] = z;
    return;
  }
  float4 v = ((const float4*)src)[off];
  ushort4 o;
  o.x = f2bf(v.x); o.y = f2bf(v.y); o.z = f2bf(v.z); o.w = f2bf(v.w);
  ((ushort4*)dst)[off] = o;
}

// ---------------------------------------------------------------------------
// Causal depthwise conv (k=4, pad 3) + bias + SiLU. bf16 in, bf16 out.
// Standalone, 4 ch/thread, 16 blocks/CU (round-10 champion config).
// ---------------------------------------------------------------------------
__global__ __launch_bounds__(256) void conv_silu4(
    const u16* __restrict__ xz, const float* __restrict__ w,
    const float* __restrict__ cb, u16* __restrict__ xc_bf) {
  int gid = blockIdx.x * 256 + threadIdx.x;  // TT*512
  int dq = (gid & 511) * 4;
  int t = gid >> 9;
  int l = t & (LL - 1);
  float wv[4][4];
#pragma unroll
  for (int j = 0; j < 4; ++j) {
    float4 ww = *(const float4*)&w[(dq + j) * 4];
    wv[j][0] = ww.x; wv[j][1] = ww.y; wv[j][2] = ww.z; wv[j][3] = ww.w;
  }
  float4 acc = *(const float4*)&cb[dq];
#pragma unroll
  for (int k = 0; k < 4; ++k) {
    int ll = l - 3 + k;
    if (ll < 0) continue;
    ushort4 xv = *(const ushort4*)&xz[(size_t)(t - 3 + k) * (2 * DI) + dq];
    acc.x += bf2f(xv.x) * wv[0][k]; acc.y += bf2f(xv.y) * wv[1][k];
    acc.z += bf2f(xv.z) * wv[2][k]; acc.w += bf2f(xv.w) * wv[3][k];
  }
  acc.x = fsilu(acc.x); acc.y = fsilu(acc.y);
  acc.z = fsilu(acc.z); acc.w = fsilu(acc.w);
  ushort4 o;
  o.x = f2bf(acc.x); o.y = f2bf(acc.y); o.z = f2bf(acc.z); o.w = f2bf(acc.w);
  *(ushort4*)&xc_bf[(size_t)t * DI + dq] = o;
}

// ---------------------------------------------------------------------------
// Chunked selective scan, SCH=32 (512 blocks/pass -> 2/CU). 3 kernels.
// ---------------------------------------------------------------------------
__global__ __launch_bounds__(256) void scan_pass1(
    const u16* __restrict__ delta, const u16* __restrict__ xc_bf,
    const float* __restrict__ xdb, const float* __restrict__ A_log,
    const unsigned* __restrict__ betak,
    float* __restrict__ hend, float* __restrict__ Ssum) {
  const int d = blockIdx.x * 256 + threadIdx.x;
  const int c = blockIdx.y;
  const int b = blockIdx.z;
  __shared__ float Bsh[SCH][16];
  const float beta = fmaxf(0.0f, -funkey(betak[0]));
  const int t0 = b * LL + c * SCH;
  for (int i = threadIdx.x; i < SCH * 16; i += 256) {
    int tt = i >> 4, n = i & 15;
    Bsh[tt][n] = xdb[(size_t)(t0 + tt) * 96 + 64 + n] + beta;
  }
  __syncthreads();
  float Av2[16];
#pragma unroll
  for (int n = 0; n < 16; ++n)
    Av2[n] = __builtin_amdgcn_exp2f(A_log[d * 16 + n] * LOG2E) * LOG2E;
  float h[16];
#pragma unroll
  for (int n = 0; n < 16; ++n) h[n] = 0.f;
  float S = 0.f;
  for (int tt = 0; tt < SCH; ++tt) {
    int t = t0 + tt;
    float dv = bf2f(delta[(size_t)t * DI + d]);
    float xv = bf2f(xc_bf[(size_t)t * DI + d]);
    float dx = dv * xv;
    S += dv;
#pragma unroll
    for (int n = 0; n < 16; ++n) {
      float a = __builtin_amdgcn_exp2f(-dv * Av2[n]);
      h[n] = a * h[n] + dx * Bsh[tt][n];
    }
  }
  size_t base = (((size_t)(b * NCH + c) * DI) + d) * 16;
#pragma unroll
  for (int n = 0; n < 16; ++n) hend[base + n] = h[n];
  Ssum[((size_t)(b * NCH + c) * DI) + d] = S;
}

__global__ __launch_bounds__(256) void scan_pass2(
    float* __restrict__ hend, const float* __restrict__ Ssum,
    const float* __restrict__ A_log) {
  int gid = blockIdx.x * 256 + threadIdx.x;   // 65536
  int n = gid & 15;
  int d = (gid >> 4) & (DI - 1);
  int b = gid >> 15;
  float Av2 = __builtin_amdgcn_exp2f(A_log[d * 16 + n] * LOG2E) * LOG2E;
  float H = 0.f;
  for (int c = 0; c < NCH; ++c) {
    size_t cb = ((size_t)(b * NCH + c) * DI) + d;
    float hl = hend[cb * 16 + n];
    float p = __builtin_amdgcn_exp2f(-Av2 * Ssum[cb]);
    hend[cb * 16 + n] = H;
    H = p * H + hl;
  }
}

__global__ __launch_bounds__(256) void scan_pass3(
    const u16* __restrict__ delta, const u16* __restrict__ xc_bf,
    const float* __restrict__ xdb, const u16* __restrict__ xz_bf,
    const float* __restrict__ A_log, const float* __restrict__ Dp,
    const unsigned* __restrict__ betak, const float* __restrict__ hstart,
    u16* __restrict__ ybf) {
  const int d = blockIdx.x * 256 + threadIdx.x;
  const int c = blockIdx.y;
  const int b = blockIdx.z;
  __shared__ float Bsh[SCH][16];
  __shared__ float Csh[SCH][16];
  const float beta = fmaxf(0.0f, -funkey(betak[0]));
  const int t0 = b * LL + c * SCH;
  for (int i = threadIdx.x; i < SCH * 16; i += 256) {
    int tt = i >> 4, n = i & 15;
    size_t row = (size_t)(t0 + tt) * 96;
    Bsh[tt][n] = xdb[row + 64 + n] + beta;
    Csh[tt][n] = xdb[row + 80 + n];
  }
  __syncthreads();
  float Av2[16];
#pragma unroll
  for (int n = 0; n < 16; ++n)
    Av2[n] = __builtin_amdgcn_exp2f(A_log[d * 16 + n] * LOG2E) * LOG2E;
  float h[16];
  size_t base = (((size_t)(b * NCH + c) * DI) + d) * 16;
#pragma unroll
  for (int n = 0; n < 16; ++n) h[n] = hstart[base + n];
  const float Dd = Dp[d];
  for (int tt = 0; tt < SCH; ++tt) {
    int t = t0 + tt;
    float dv = bf2f(delta[(size_t)t * DI + d]);
    float xv = bf2f(xc_bf[(size_t)t * DI + d]);
    float dx = dv * xv;
    float yv = 0.f;
#pragma unroll
    for (int n = 0; n < 16; ++n) {
      float a = __builtin_amdgcn_exp2f(-dv * Av2[n]);
      h[n] = a * h[n] + dx * Bsh[tt][n];
      yv += h[n] * Csh[tt][n];
    }
    float zv = bf2f(xz_bf[(size_t)t * (2 * DI) + DI + d]);
    float out = (yv + xv * Dd) * fsilu(zv);
    ybf[(size_t)t * DI + d] = f2bf(out);
  }
}

extern "C" void kernel_launch(void* const* d_in, const int* in_sizes, int n_in,
                              void* d_out, int out_size, void* d_ws, size_t ws_size,
                              hipStream_t stream) {
  const float* hs      = (const float*)d_in[0];
  const float* W_in    = (const float*)d_in[1];
  const float* conv_w  = (const float*)d_in[2];
  const float* conv_b  = (const float*)d_in[3];
  const float* W_x     = (const float*)d_in[4];
  const float* W_dt    = (const float*)d_in[5];
  const float* dt_bias = (const float*)d_in[6];
  const float* W_out   = (const float*)d_in[7];
  const float* A_log   = (const float*)d_in[8];
  const float* Dp      = (const float*)d_in[9];
  float* out = (float*)d_out;

  float* ws       = (float*)d_ws;
  float* xz_bfR   = ws;                                  // 4,194,304 f
  float* xcv_bfR  = xz_bfR + (size_t)TT * 2 * DI / 2;    // 2,097,152 f
  float* xdb      = xcv_bfR + (size_t)TT * DI / 2;       //   196,608 f
  float* dlt_bfR  = xdb + (size_t)TT * 96;               // 2,097,152 f
  float* betab    = dlt_bfR + (size_t)TT * DI / 2;       //        64 f
  float* hend     = betab + 64;                          // 2,097,152 f
  float* Ssum     = hend + (size_t)NB * NCH * DI * 16;   //   131,072 f
  float* hs_bfR   = Ssum + (size_t)NB * NCH * DI;        // 1,048,576 f
  float* win_bfR  = hs_bfR + (size_t)TT * DM / 2;        // 2,097,152 f
  float* wout_bfR = win_bfR + (size_t)2 * DI * DM / 2;   // 1,048,576 f
  float* wx_bfR   = wout_bfR + (size_t)DM * DI / 2;      //   131,072 f
  float* wdt_bfR  = wx_bfR + 131072;                     //    65,536 f

  u16* xz_bf   = (u16*)xz_bfR;
  u16* xcv_bf  = (u16*)xcv_bfR;
  u16* dlt_bf  = (u16*)dlt_bfR;
  u16* hs_bf   = (u16*)hs_bfR;
  u16* win_bf  = (u16*)win_bfR;
  u16* wout_bf = (u16*)wout_bfR;
  u16* wx_bf   = (u16*)wx_bfR;
  u16* wdt_bf  = (u16*)wdt_bfR;
  unsigned* betakey = (unsigned*)betab;
  u16* ybf     = (u16*)win_bfR;   // aliases win_bf (dead after GEMM1)

  dim3 blk(256);

  // 1) bf16 casts + zero xdb/out + betakey init
  cast_all<<<10816, blk, 0, stream>>>(hs, W_in, W_out, W_x, W_dt,
                                      hs_bf, win_bf, wout_bf, wx_bf, wdt_bf,
                                      xdb, out, betakey);

  // 2) xz = hs @ W_in^T  (2048x4096x1024) bf16 GLDS, PIPE3 counted-vmcnt
  gemm_k<128, 128, 0, 1, 0, 0, 0, 1>
      <<<dim3(4096 / 128, TT / 128), blk, 0, stream>>>(
      hs_bf, win_bf, xz_bf, TT, 2 * DI, DM, DM, DM, DM,
      nullptr, nullptr, nullptr);

  // 3) conv + silu -> xcv_bf (standalone, 16 blocks/CU)
  conv_silu4<<<(TT * DI / 4) / 256, blk, 0, stream>>>(xz_bf, conv_w, conv_b, xcv_bf);

  // 4) x_dbl: (2048x128x2048) bf16 GLDS both, split-K=8, atomicAdd cols<96
  gemm_k<64, 128, 0, 2, 96, 0, 0, 0>
      <<<dim3(1, TT / 64, 8), blk, 0, stream>>>(
      xcv_bf, wx_bf, xdb, TT, 128, DI, DI, DI, DI / 8,
      nullptr, nullptr, nullptr);

  // 5) delta: A = xdb cols0..63 fp32 reg-staged (lda=96), B = wdt_bf GLDS,
  //    softplus/clip -> bf16 dlt; blocks 0..63 also reduce beta-min (BMIN)
  gemm_k<64, 128, 1, 1, 0, 1, 1, 0>
      <<<dim3(DI / 128, TT / 64), blk, 0, stream>>>(
      xdb, wdt_bf, dlt_bf, TT, DI, DTR, 96, DTR, DTR,
      dt_bias, xdb, betakey);

  // 6) chunked selective scan -> ybf
  scan_pass1<<<dim3(DI / 256, NCH, NB), blk, 0, stream>>>(
      dlt_bf, xcv_bf, xdb, A_log, betakey, hend, Ssum);
  scan_pass2<<<(NB * DI * DS) / 256, blk, 0, stream>>>(hend, Ssum, A_log);
  scan_pass3<<<dim3(DI / 256, NCH, NB), blk, 0, stream>>>(
      dlt_bf, xcv_bf, xdb, xz_bf, A_log, Dp, betakey, hend, ybf);

  // 7) out = y @ W_out^T (2048x1024x2048) bf16 GLDS, split-K=4 atomic, PIPE3
  gemm_k<128, 128, 0, 2, 0, 0, 0, 1>
      <<<dim3(DM / 128, TT / 128, 4), blk, 0, stream>>>(
      ybf, wout_bf, out, TT, DM, DI, DI, DI, DI / 4,
      nullptr, nullptr, nullptr);
}